// Round 8
// baseline (32.604 us; speedup 1.0000x reference)
//
#include <hip/hip_runtime.h>

// CPAB 1D warp + linear resample — fused, 2-round grid + XCD colocation:
//   * JPB=128, grid=4096 (2 rounds/CU): backfill smooths straggler tail,
//     round-2 ODE overlaps round-1 memory phase
//   * bijective swizzle: all 16 blocks of one batch land on one XCD (L2 share)
//   * NT stores, staged+fenced gather loads, q-scaled ODE (from R6/R7)
// x:     [B, LIN, C]  f32   (d_in[0])
// theta: [B, D]       f32   (d_in[1])
// basis: [2*NC, D]    f32   (d_in[2])
// out:   [B, OUTLEN, C] f32

#define NSTEPS 64
#define NC     32
#define DD     33      // nC + 1
#define LIN    2048
#define CCH    32
#define OUTLEN 2048
#define JPW    32      // j positions per wave
#define WPB    4       // waves per block
#define JPB    (JPW * WPB)       // 128
#define BPB    (OUTLEN / JPB)    // 16 blocks per batch
#define NXCD   8

typedef float f32x4 __attribute__((ext_vector_type(4)));

__global__ __launch_bounds__(256) void cpab_warp_kernel(
    const float* __restrict__ x,
    const float* __restrict__ theta,
    const float* __restrict__ basis,
    float* __restrict__ out)
{
    // wave-private LDS: same-wave write->read ordered by lgkmcnt, no barrier
    __shared__ float2 ctab[WPB][NC];    // (c1, c0*NC) per cell: q' = c1*q + c0n
    __shared__ float2 iw[WPB][JPW];     // (w, i0) per j

    const int t    = threadIdx.x;
    const int wave = t >> 6;
    const int lane = t & 63;

    // Bijective XCD swizzle (dispatch d -> d%8 picks XCD on MI355X):
    // all BPB blocks of one b get the same d%8 -> share that XCD's L2.
    // d = (b%8) + 8*(part + BPB*(b/8)), inverted here:
    const int d    = blockIdx.x;
    const int xcd  = d & (NXCD - 1);
    const int r    = d >> 3;
    const int part = r & (BPB - 1);
    const int bh   = r >> 4;             // r / BPB, BPB=16
    const int b     = bh * NXCD + xcd;
    const int jbase = part * JPB + wave * JPW;

    const float dt = 1.0f / (float)NSTEPS;

    // Phase 0 (per wave): lane k computes A_k = basis[k,:] . theta[b,:]
    float acc = 0.0f;
    {
        const float* bs = basis + lane * DD;
        const float* th = theta + b * DD;
        #pragma unroll
        for (int dd = 0; dd < DD; ++dd) acc = fmaf(bs[dd], th[dd], acc);
    }
    {
        // cell c: a = A[2c], b = A[2c+1] -> c1 = 1 + a*dt, c0n = b*dt*NC
        int c = lane & (NC - 1);
        float a  = __shfl(acc, 2 * c);
        float bb = __shfl(acc, 2 * c + 1);
        if (lane < NC) ctab[wave][c] = make_float2(fmaf(a, dt, 1.0f), bb * dt * (float)NC);
    }

    // Phase 1 (per wave): integrate one trajectory per lane, q = phi*NC
    // (both 32-lane halves compute the same j; low half writes)
    {
        const int jl = lane & (JPW - 1);
        const int j  = jbase + jl;
        float q = (float)j * ((float)NC / (float)(OUTLEN - 1));
        const float2* ct = ctab[wave];
        #pragma unroll
        for (int s = 0; s < NSTEPS; ++s) {
            // cell = trunc(clamp(q,0,31)) == reference clip(floor(phi*NC),0,31)
            float f = fminf(fmaxf(q, 0.0f), (float)(NC - 1));   // v_med3
            float2 cc = ct[(int)f];
            q = fmaf(cc.x, q, cc.y);
        }
        // p = clamp(phi,0,1)*(LIN-1) with phi = q/NC
        float p = fminf(fmaxf(q * ((float)(LIN - 1) / (float)NC), 0.0f), (float)(LIN - 1));
        int i0 = min((int)p, LIN - 2);           // p >= 0, trunc == floor
        if (lane < JPW) iw[wave][jl] = make_float2(p - (float)i0, (float)i0);
    }

    // Phase 2 (per wave): resample 32 j x 32 c as f32x4, 4 its.
    // Issue ALL 8 loads, fence the scheduler, then lerp + NT-store.
    const f32x4* xb = (const f32x4*)(x + (size_t)b * (LIN * CCH));
    f32x4* ob = (f32x4*)(out + ((size_t)b * OUTLEN + jbase) * CCH);
    const int c4  = lane & 7;        // f32x4 column within row (32 ch = 8 f32x4)
    const int jl0 = lane >> 3;       // 0..7

    float2 f[JPW / 8];
    #pragma unroll
    for (int it = 0; it < JPW / 8; ++it) f[it] = iw[wave][it * 8 + jl0];

    f32x4 g0[JPW / 8], g1[JPW / 8];
    #pragma unroll
    for (int it = 0; it < JPW / 8; ++it) {
        int i0 = (int)f[it].y;
        g0[it] = xb[i0 * (CCH / 4) + c4];
        g1[it] = xb[(i0 + 1) * (CCH / 4) + c4];
    }
    __builtin_amdgcn_sched_barrier(0);   // keep all loads issued before any use

    #pragma unroll
    for (int it = 0; it < JPW / 8; ++it) {
        float w = f[it].x;
        f32x4 rr = g0[it] + w * (g1[it] - g0[it]);
        __builtin_nontemporal_store(rr, &ob[(it * 8 + jl0) * (CCH / 4) + c4]);
    }
}

extern "C" void kernel_launch(void* const* d_in, const int* in_sizes, int n_in,
                              void* d_out, int out_size, void* d_ws, size_t ws_size,
                              hipStream_t stream) {
    const float* x     = (const float*)d_in[0];
    const float* theta = (const float*)d_in[1];
    const float* basis = (const float*)d_in[2];
    float* out = (float*)d_out;

    const int B = in_sizes[1] / DD;                 // 256
    const int grid = B * BPB;                       // 4096 blocks, 2 rounds/CU
    cpab_warp_kernel<<<grid, 256, 0, stream>>>(x, theta, basis, out);
}

// Round 9
// 29.286 us; speedup vs baseline: 1.1133x; 1.1133x over previous
//
#include <hip/hip_runtime.h>

// CPAB 1D warp + linear resample — fused; ODE table via lane shuffles:
//   * coefficient lookup = 2x ds_bpermute (no LDS table, shorter dep chain)
//   * NT stores, staged+fenced gather loads, q-scaled ODE (R6/R7)
// x:     [B, LIN, C]  f32   (d_in[0])
// theta: [B, D]       f32   (d_in[1])
// basis: [2*NC, D]    f32   (d_in[2])
// out:   [B, OUTLEN, C] f32

#define NSTEPS 64
#define NC     32
#define DD     33      // nC + 1
#define LIN    2048
#define CCH    32
#define OUTLEN 2048
#define JPW    64      // j positions per wave
#define WPB    4       // waves per block
#define JPB    (JPW * WPB)   // 256

typedef float f32x4 __attribute__((ext_vector_type(4)));

__global__ __launch_bounds__(256) void cpab_warp_kernel(
    const float* __restrict__ x,
    const float* __restrict__ theta,
    const float* __restrict__ basis,
    float* __restrict__ out)
{
    // wave-private LDS: same-wave write->read ordered by lgkmcnt, no barrier
    __shared__ float2 iw[WPB][JPW];     // (w, i0) per j

    const int t    = threadIdx.x;
    const int wave = t >> 6;
    const int lane = t & 63;
    const int blocksPerB = OUTLEN / JPB;            // 8
    const int b     = blockIdx.x / blocksPerB;
    const int jbase = (blockIdx.x % blocksPerB) * JPB + wave * JPW;

    const float dt = 1.0f / (float)NSTEPS;

    // Phase 0 (per wave): lane k computes A_k = basis[k,:] . theta[b,:],
    // then redistribute so lane l (l<NC) holds cell l's (c1, c0n) IN REGISTERS.
    float acc = 0.0f;
    {
        const float* bs = basis + lane * DD;
        const float* th = theta + b * DD;
        #pragma unroll
        for (int dd = 0; dd < DD; ++dd) acc = fmaf(bs[dd], th[dd], acc);
    }
    // cell c: a = A[2c], b = A[2c+1] -> c1 = 1 + a*dt, c0n = b*dt*NC
    const float vc1  = fmaf(__shfl(acc, (2 * lane) & 63), dt, 1.0f);
    const float vc0n = __shfl(acc, (2 * lane + 1) & 63) * (dt * (float)NC);

    // Phase 1 (per wave): integrate one trajectory per lane, q = phi*NC.
    // Per-step lookup = two independent lane shuffles (ds_bpermute), no LDS.
    {
        const int j = jbase + lane;
        float q = (float)j * ((float)NC / (float)(OUTLEN - 1));
        #pragma unroll
        for (int s = 0; s < NSTEPS; ++s) {
            // cell = trunc(clamp(q,0,31)) == reference clip(floor(phi*NC),0,31)
            float f = fminf(fmaxf(q, 0.0f), (float)(NC - 1));   // v_med3
            int   c = (int)f;
            float c1 = __shfl(vc1, c);
            float c0 = __shfl(vc0n, c);
            q = fmaf(c1, q, c0);
        }
        // p = clamp(phi,0,1)*(LIN-1) with phi = q/NC
        float p = fminf(fmaxf(q * ((float)(LIN - 1) / (float)NC), 0.0f), (float)(LIN - 1));
        int i0 = min((int)p, LIN - 2);           // p >= 0, trunc == floor
        iw[wave][lane] = make_float2(p - (float)i0, (float)i0);
    }

    // Phase 2 (per wave): resample 64 j x 32 c as f32x4, 8 its.
    // Issue ALL 16 loads, fence the scheduler, then lerp + NT-store.
    const f32x4* xb = (const f32x4*)(x + (size_t)b * (LIN * CCH));
    f32x4* ob = (f32x4*)(out + ((size_t)b * OUTLEN + jbase) * CCH);
    const int c4  = lane & 7;        // f32x4 column within row (32 ch = 8 f32x4)
    const int jl0 = lane >> 3;       // 0..7

    float2 f[8];
    #pragma unroll
    for (int it = 0; it < 8; ++it) f[it] = iw[wave][it * 8 + jl0];

    f32x4 g0[8], g1[8];
    #pragma unroll
    for (int it = 0; it < 8; ++it) {
        int i0 = (int)f[it].y;
        g0[it] = xb[i0 * (CCH / 4) + c4];
        g1[it] = xb[(i0 + 1) * (CCH / 4) + c4];
    }
    __builtin_amdgcn_sched_barrier(0);   // keep loads issued before any use

    #pragma unroll
    for (int it = 0; it < 8; ++it) {
        float w = f[it].x;
        f32x4 r = g0[it] + w * (g1[it] - g0[it]);
        __builtin_nontemporal_store(r, &ob[(it * 8 + jl0) * (CCH / 4) + c4]);
    }
}

extern "C" void kernel_launch(void* const* d_in, const int* in_sizes, int n_in,
                              void* d_out, int out_size, void* d_ws, size_t ws_size,
                              hipStream_t stream) {
    const float* x     = (const float*)d_in[0];
    const float* theta = (const float*)d_in[1];
    const float* basis = (const float*)d_in[2];
    float* out = (float*)d_out;

    const int B = in_sizes[1] / DD;                 // 256
    const int grid = B * (OUTLEN / JPB);            // 2048 blocks
    cpab_warp_kernel<<<grid, 256, 0, stream>>>(x, theta, basis, out);
}

// Round 10
// 28.369 us; speedup vs baseline: 1.1493x; 1.0324x over previous
//
#include <hip/hip_runtime.h>

// CPAB 1D warp + linear resample — fused; 2 interleaved ODE chains per lane:
//   * JPW=128: each lane integrates q0,q1 (independent dep chains overlap in
//     the LDS/VALU pipes) -> half as many serial ODE epochs chip-wide
//   * LDS ctab (R7), staged+fenced gather loads in 2 halves, NT stores
// x:     [B, LIN, C]  f32   (d_in[0])
// theta: [B, D]       f32   (d_in[1])
// basis: [2*NC, D]    f32   (d_in[2])
// out:   [B, OUTLEN, C] f32

#define NSTEPS 64
#define NC     32
#define DD     33      // nC + 1
#define LIN    2048
#define CCH    32
#define OUTLEN 2048
#define JPW    128     // j positions per wave (2 chains x 64 lanes)
#define WPB    4       // waves per block
#define JPB    (JPW * WPB)   // 512

typedef float f32x4 __attribute__((ext_vector_type(4)));

__global__ __launch_bounds__(256, 4) void cpab_warp_kernel(
    const float* __restrict__ x,
    const float* __restrict__ theta,
    const float* __restrict__ basis,
    float* __restrict__ out)
{
    // wave-private LDS: same-wave write->read ordered by lgkmcnt, no barrier
    __shared__ float2 ctab[WPB][NC];    // (c1, c0*NC) per cell: q' = c1*q + c0n
    __shared__ float2 iw[WPB][JPW];     // (w, i0) per j

    const int t    = threadIdx.x;
    const int wave = t >> 6;
    const int lane = t & 63;
    const int blocksPerB = OUTLEN / JPB;            // 4
    const int b     = blockIdx.x / blocksPerB;
    const int jbase = (blockIdx.x % blocksPerB) * JPB + wave * JPW;

    const float dt = 1.0f / (float)NSTEPS;

    // Phase 0 (per wave): lane k computes A_k = basis[k,:] . theta[b,:]
    float acc = 0.0f;
    {
        const float* bs = basis + lane * DD;
        const float* th = theta + b * DD;
        #pragma unroll
        for (int dd = 0; dd < DD; ++dd) acc = fmaf(bs[dd], th[dd], acc);
    }
    {
        // cell c: a = A[2c], b = A[2c+1] -> c1 = 1 + a*dt, c0n = b*dt*NC
        int c = lane & (NC - 1);
        float a  = __shfl(acc, 2 * c);
        float bb = __shfl(acc, 2 * c + 1);
        if (lane < NC) ctab[wave][c] = make_float2(fmaf(a, dt, 1.0f), bb * dt * (float)NC);
    }

    // Phase 1 (per wave): two interleaved independent chains per lane
    {
        const int j0 = jbase + lane;
        const int j1 = jbase + 64 + lane;
        float q0 = (float)j0 * ((float)NC / (float)(OUTLEN - 1));
        float q1 = (float)j1 * ((float)NC / (float)(OUTLEN - 1));
        const float2* ct = ctab[wave];
        #pragma unroll
        for (int s = 0; s < NSTEPS; ++s) {
            float f0 = fminf(fmaxf(q0, 0.0f), (float)(NC - 1));   // v_med3
            float f1 = fminf(fmaxf(q1, 0.0f), (float)(NC - 1));
            float2 cc0 = ct[(int)f0];
            float2 cc1 = ct[(int)f1];
            q0 = fmaf(cc0.x, q0, cc0.y);
            q1 = fmaf(cc1.x, q1, cc1.y);
        }
        float p0 = fminf(fmaxf(q0 * ((float)(LIN - 1) / (float)NC), 0.0f), (float)(LIN - 1));
        float p1 = fminf(fmaxf(q1 * ((float)(LIN - 1) / (float)NC), 0.0f), (float)(LIN - 1));
        int i00 = min((int)p0, LIN - 2);         // p >= 0, trunc == floor
        int i01 = min((int)p1, LIN - 2);
        iw[wave][lane]      = make_float2(p0 - (float)i00, (float)i00);
        iw[wave][64 + lane] = make_float2(p1 - (float)i01, (float)i01);
    }

    // Phase 2 (per wave): resample 128 j x 32 c as f32x4, two halves of
    // 8 its; per half: stage 16 loads, fence, lerp + NT-store.
    const f32x4* xb = (const f32x4*)(x + (size_t)b * (LIN * CCH));
    f32x4* ob = (f32x4*)(out + ((size_t)b * OUTLEN + jbase) * CCH);
    const int c4  = lane & 7;        // f32x4 column within row (32 ch = 8 f32x4)
    const int jl0 = lane >> 3;       // 0..7

    #pragma unroll
    for (int half = 0; half < 2; ++half) {
        float2 f[8];
        #pragma unroll
        for (int it = 0; it < 8; ++it) f[it] = iw[wave][half * 64 + it * 8 + jl0];

        f32x4 g0[8], g1[8];
        #pragma unroll
        for (int it = 0; it < 8; ++it) {
            int i0 = (int)f[it].y;
            g0[it] = xb[i0 * (CCH / 4) + c4];
            g1[it] = xb[(i0 + 1) * (CCH / 4) + c4];
        }
        __builtin_amdgcn_sched_barrier(0);   // keep loads issued before any use

        #pragma unroll
        for (int it = 0; it < 8; ++it) {
            float w = f[it].x;
            f32x4 r = g0[it] + w * (g1[it] - g0[it]);
            __builtin_nontemporal_store(r, &ob[(half * 64 + it * 8 + jl0) * (CCH / 4) + c4]);
        }
    }
}

extern "C" void kernel_launch(void* const* d_in, const int* in_sizes, int n_in,
                              void* d_out, int out_size, void* d_ws, size_t ws_size,
                              hipStream_t stream) {
    const float* x     = (const float*)d_in[0];
    const float* theta = (const float*)d_in[1];
    const float* basis = (const float*)d_in[2];
    float* out = (float*)d_out;

    const int B = in_sizes[1] / DD;                 // 256
    const int grid = B * (OUTLEN / JPB);            // 1024 blocks
    cpab_warp_kernel<<<grid, 256, 0, stream>>>(x, theta, basis, out);
}